// Round 3
// baseline (520.555 us; speedup 1.0000x reference)
//
#include <hip/hip_runtime.h>

#define N_NODES 200000
#define DIM 256
#define G_SEG 1024
#define MT 96         // rows per block (96 < min segment size 195 -> <=2 segs/block)
#define LDA 260       // LDS row stride in bf16 elems (256 + 4 pad -> 2-way-free b128 reads)
#define NT 6          // 16-row m-tiles per block
#define KSTEPS 8      // 256 / 32

typedef __bf16 bf16x8 __attribute__((ext_vector_type(8)));
typedef float f32x4 __attribute__((ext_vector_type(4)));
typedef unsigned short us16_t __attribute__((ext_vector_type(16)));
typedef unsigned short us8_t __attribute__((ext_vector_type(8)));
typedef unsigned short us4_t __attribute__((ext_vector_type(4)));

__device__ __forceinline__ unsigned short f2bf(float f) {
  unsigned int u = __float_as_uint(f);
  u = u + 0x7FFFu + ((u >> 16) & 1u);   // round-to-nearest-even
  return (unsigned short)(u >> 16);
}

__device__ __forceinline__ bf16x8 ld_frag(const unsigned short* p) {
  us8_t r = *(const us8_t*)p;
  return __builtin_bit_cast(bf16x8, r);
}

__device__ __forceinline__ float silu(float v) {
  return v * __builtin_amdgcn_rcpf(1.f + __expf(-v));
}

// Stage MT rows x 256 cols of fp32 X into LDS as bf16 (padded stride LDA).
__device__ __forceinline__ void stage_x(const float* __restrict__ X,
                                        unsigned short* A, int base, int tid) {
  #pragma unroll 4
  for (int i = 0; i < MT / 4; ++i) {   // 24 iters: MT*64 float4s / 256 threads
    int flat = i * 256 + tid;
    int row = flat >> 6;
    int c4 = flat & 63;
    int grow = base + row;
    float4 v = make_float4(0.f, 0.f, 0.f, 0.f);
    if (grow < N_NODES) v = *(const float4*)(X + (size_t)grow * DIM + c4 * 4);
    us4_t h;
    h[0] = f2bf(v.x); h[1] = f2bf(v.y); h[2] = f2bf(v.z); h[3] = f2bf(v.w);
    *(us4_t*)(A + row * LDA + c4 * 4) = h;
  }
}

// Transposed GEMM: D[feature][node] = W_tile x X_tile, with explicit
// double-buffered weight-fragment prefetch (covers the L2 latency).
// acc[t][u]: node = t*16 + (lane&15), feature = wcol0 + u*16 + (lane>>4)*4 + r.
__device__ __forceinline__ void gemm_k256_T(const unsigned short* __restrict__ Wb,
                                            const unsigned short* A,
                                            f32x4 acc[NT][4],
                                            int wcol0, int quad, int l15) {
  const unsigned short* wp = Wb + (size_t)(wcol0 + l15) * 256 + quad * 8;
  bf16x8 wcur[4], wnxt[4];
  #pragma unroll
  for (int u = 0; u < 4; ++u) wcur[u] = ld_frag(wp + u * 16 * 256);
  #pragma unroll 1
  for (int ks = 0; ks < KSTEPS; ++ks) {
    if (ks + 1 < KSTEPS) {
      #pragma unroll
      for (int u = 0; u < 4; ++u)
        wnxt[u] = ld_frag(wp + u * 16 * 256 + (ks + 1) * 32);
    }
    int koff = ks * 32 + quad * 8;
    #pragma unroll
    for (int t = 0; t < NT; ++t) {
      bf16x8 xfr = ld_frag(A + (t * 16 + l15) * LDA + koff);
      #pragma unroll
      for (int u = 0; u < 4; ++u)
        acc[t][u] = __builtin_amdgcn_mfma_f32_16x16x32_bf16(wcur[u], xfr, acc[t][u], 0, 0, 0);
    }
    #pragma unroll
    for (int u = 0; u < 4; ++u) wcur[u] = wnxt[u];
  }
}

__device__ __forceinline__ void zero_acc(f32x4 acc[NT][4]) {
  #pragma unroll
  for (int t = 0; t < NT; ++t)
    #pragma unroll
    for (int u = 0; u < 4; ++u)
      acc[t][u] = (f32x4){0.f, 0.f, 0.f, 0.f};
}

// Kernel 0: zero out + denom (blocks 0..1024), transpose weights to bf16 [n][k]
// with coalesced LDS tiles (blocks 1025..1040).
__global__ __launch_bounds__(256) void k_prep(
    const float* __restrict__ W1, const float* __restrict__ W2,
    const float* __restrict__ W3, const float* __restrict__ aW1,
    unsigned short* __restrict__ Wb1, unsigned short* __restrict__ Wb2,
    unsigned short* __restrict__ Wb3, unsigned short* __restrict__ aWb1,
    float* __restrict__ out, float* __restrict__ denom) {
  __shared__ float tlds[64][257];
  int b = blockIdx.x, tid = threadIdx.x;
  if (b < 1024) {
    out[b * 256 + tid] = 0.f;
    return;
  }
  if (b == 1024) {
    #pragma unroll
    for (int i = 0; i < 4; ++i) denom[tid * 4 + i] = 0.f;
    return;
  }
  int bb = b - 1025;                  // 0..15
  int mat = bb >> 2, kc = bb & 3, k0 = kc * 64;
  const float* W = (mat == 0) ? W1 : (mat == 1) ? W2 : (mat == 2) ? W3 : aW1;
  unsigned short* Wb = (mat == 0) ? Wb1 : (mat == 1) ? Wb2 : (mat == 2) ? Wb3 : aWb1;
  #pragma unroll 8
  for (int i = 0; i < 64; ++i)
    tlds[i][tid] = W[(size_t)(k0 + i) * 256 + tid];
  __syncthreads();
  #pragma unroll
  for (int rep = 0; rep < 4; ++rep) {
    int flat = rep * 256 + tid;       // 0..1023
    int n = flat >> 2, c = flat & 3;
    us16_t v;
    #pragma unroll
    for (int j = 0; j < 16; ++j) v[j] = f2bf(tlds[c * 16 + j][n]);
    *(us16_t*)(Wb + (size_t)n * 256 + k0 + c * 16) = v;
  }
}

// Fused heavy kernel: one staging of X, attention GEMM + 3-stage MLP,
// unnormalized weighted segment sums into out + denom.
__global__ __launch_bounds__(256, 3) void k_fused(
    const float* __restrict__ X, const int* __restrict__ batch,
    const unsigned short* __restrict__ aWb1, const float* __restrict__ ab1,
    const float* __restrict__ aW2, const float* __restrict__ ab2,
    const unsigned short* __restrict__ Wb1, const float* __restrict__ b1,
    const unsigned short* __restrict__ Wb2, const float* __restrict__ b2,
    const unsigned short* __restrict__ Wb3, const float* __restrict__ b3,
    float* __restrict__ out, float* __restrict__ denom) {
  __shared__ unsigned short a_lds[MT * LDA];   // 49920 B
  __shared__ float l_part[4][MT];              // per-wave logit partials
  __shared__ float ew0[MT], ew1[MT];
  __shared__ float seg_lds[2];
  int tid = threadIdx.x;
  int base = blockIdx.x * MT;
  stage_x(X, a_lds, base, tid);
  if (tid < 2) seg_lds[tid] = 0.f;
  __syncthreads();

  int wave = tid >> 6, lane = tid & 63, quad = lane >> 4, l15 = lane & 15;
  int wcol0 = wave * 64;
  int fq = wcol0 + quad * 4;          // this lane's feature base for u=0
  f32x4 acc[NT][4];

  // ---- attention logits GEMM ----
  zero_acc(acc);
  gemm_k256_T(aWb1, a_lds, acc, wcol0, quad, l15);
  {
    float4 ab1c[4], aw2c[4];
    #pragma unroll
    for (int u = 0; u < 4; ++u) {
      ab1c[u] = *(const float4*)(ab1 + fq + u * 16);
      aw2c[u] = *(const float4*)(aW2 + fq + u * 16);
    }
    #pragma unroll
    for (int t = 0; t < NT; ++t) {
      float p = 0.f;
      #pragma unroll
      for (int u = 0; u < 4; ++u) {
        const float* bb = (const float*)&ab1c[u];
        const float* ww = (const float*)&aw2c[u];
        #pragma unroll
        for (int r = 0; r < 4; ++r)
          p += silu(acc[t][u][r] + bb[r]) * ww[r];
      }
      p += __shfl_xor(p, 16); p += __shfl_xor(p, 32);
      if (quad == 0) l_part[wave][t * 16 + l15] = p;   // no atomics
    }
  }

  // ---- MLP stage 1: h1 = silu(X @ W1 + b1) ----
  zero_acc(acc);
  gemm_k256_T(Wb1, a_lds, acc, wcol0, quad, l15);
  __syncthreads();   // a_lds reads done by all waves; l_part complete
  if (tid < MT) {
    int grow = base + tid;
    float e = 0.f; int ds = 0;
    if (grow < N_NODES) {
      e = __expf(l_part[0][tid] + l_part[1][tid] + l_part[2][tid] + l_part[3][tid] + ab2[0]);
      ds = batch[grow] - batch[base];   // 0 or 1
    }
    ew0[tid] = ds ? 0.f : e;
    ew1[tid] = ds ? e : 0.f;
    if (e != 0.f) atomicAdd(&seg_lds[ds], e);
  }
  {
    float4 bc[4];
    #pragma unroll
    for (int u = 0; u < 4; ++u) bc[u] = *(const float4*)(b1 + fq + u * 16);
    #pragma unroll
    for (int t = 0; t < NT; ++t)
      #pragma unroll
      for (int u = 0; u < 4; ++u) {
        const float* bb = (const float*)&bc[u];
        us4_t h;
        #pragma unroll
        for (int r = 0; r < 4; ++r)
          h[r] = f2bf(silu(acc[t][u][r] + bb[r]));
        *(us4_t*)(a_lds + (t * 16 + l15) * LDA + fq + u * 16) = h;
      }
  }
  __syncthreads();

  // ---- MLP stage 2: h2 = silu(h1 @ W2 + b2) ----
  zero_acc(acc);
  gemm_k256_T(Wb2, a_lds, acc, wcol0, quad, l15);
  __syncthreads();
  {
    float4 bc[4];
    #pragma unroll
    for (int u = 0; u < 4; ++u) bc[u] = *(const float4*)(b2 + fq + u * 16);
    #pragma unroll
    for (int t = 0; t < NT; ++t)
      #pragma unroll
      for (int u = 0; u < 4; ++u) {
        const float* bb = (const float*)&bc[u];
        us4_t h;
        #pragma unroll
        for (int r = 0; r < 4; ++r)
          h[r] = f2bf(silu(acc[t][u][r] + bb[r]));
        *(us4_t*)(a_lds + (t * 16 + l15) * LDA + fq + u * 16) = h;
      }
  }
  __syncthreads();

  // ---- MLP stage 3: x = h2 @ W3 + b3, weighted segment reduce ----
  zero_acc(acc);
  gemm_k256_T(Wb3, a_lds, acc, wcol0, quad, l15);
  {
    float4 bc[4];
    #pragma unroll
    for (int u = 0; u < 4; ++u) bc[u] = *(const float4*)(b3 + fq + u * 16);
    float s0a[4][4], s1a[4][4];
    #pragma unroll
    for (int u = 0; u < 4; ++u)
      #pragma unroll
      for (int r = 0; r < 4; ++r) { s0a[u][r] = 0.f; s1a[u][r] = 0.f; }
    #pragma unroll
    for (int t = 0; t < NT; ++t) {
      float w0 = ew0[t * 16 + l15];
      float w1 = ew1[t * 16 + l15];
      #pragma unroll
      for (int u = 0; u < 4; ++u) {
        const float* bb = (const float*)&bc[u];
        #pragma unroll
        for (int r = 0; r < 4; ++r) {
          float x = acc[t][u][r] + bb[r];
          s0a[u][r] += x * w0;
          s1a[u][r] += x * w1;
        }
      }
    }
    int s0 = batch[base];
    #pragma unroll
    for (int u = 0; u < 4; ++u)
      #pragma unroll
      for (int r = 0; r < 4; ++r) {
        float a0 = s0a[u][r];
        a0 += __shfl_xor(a0, 1); a0 += __shfl_xor(a0, 2);
        a0 += __shfl_xor(a0, 4); a0 += __shfl_xor(a0, 8);
        float a1 = s1a[u][r];
        a1 += __shfl_xor(a1, 1); a1 += __shfl_xor(a1, 2);
        a1 += __shfl_xor(a1, 4); a1 += __shfl_xor(a1, 8);
        if (l15 == 0) {
          int col = fq + u * 16 + r;
          atomicAdd(&out[(size_t)s0 * 256 + col], a0);
          if (s0 + 1 < G_SEG && a1 != 0.f)
            atomicAdd(&out[(size_t)(s0 + 1) * 256 + col], a1);
        }
      }
    if (tid < 2) {
      float v = seg_lds[tid];
      if (v != 0.f) atomicAdd(&denom[s0 + tid], v);
    }
  }
}

// Kernel 2: out[g][c] /= denom[g]
__global__ __launch_bounds__(256) void k_final(float* __restrict__ out,
                                               const float* __restrict__ denom) {
  int b = blockIdx.x, tid = threadIdx.x;
  out[b * 256 + tid] /= denom[b];
}

extern "C" void kernel_launch(void* const* d_in, const int* in_sizes, int n_in,
                              void* d_out, int out_size, void* d_ws, size_t ws_size,
                              hipStream_t stream) {
  const float* X    = (const float*)d_in[0];
  const int* batch  = (const int*)d_in[1];
  const float* W1  = (const float*)d_in[3];
  const float* b1  = (const float*)d_in[4];
  const float* W2  = (const float*)d_in[5];
  const float* b2  = (const float*)d_in[6];
  const float* W3  = (const float*)d_in[7];
  const float* b3  = (const float*)d_in[8];
  const float* aW1 = (const float*)d_in[9];
  const float* ab1 = (const float*)d_in[10];
  const float* aW2 = (const float*)d_in[11];
  const float* ab2 = (const float*)d_in[12];
  float* out = (float*)d_out;

  char* ws = (char*)d_ws;
  unsigned short* Wb1  = (unsigned short*)(ws);
  unsigned short* Wb2  = (unsigned short*)(ws + 131072);
  unsigned short* Wb3  = (unsigned short*)(ws + 262144);
  unsigned short* aWb1 = (unsigned short*)(ws + 393216);
  float* denom = (float*)(ws + 524288);

  hipLaunchKernelGGL(k_prep, dim3(1041), dim3(256), 0, stream,
                     W1, W2, W3, aW1, Wb1, Wb2, Wb3, aWb1, out, denom);
  int nblk = (N_NODES + MT - 1) / MT;  // 2084
  hipLaunchKernelGGL(k_fused, dim3(nblk), dim3(256), 0, stream,
                     X, batch, aWb1, ab1, aW2, ab2,
                     Wb1, b1, Wb2, b2, Wb3, b3, out, denom);
  hipLaunchKernelGGL(k_final, dim3(G_SEG), dim3(256), 0, stream, out, denom);
}